// Round 3
// baseline (822.907 us; speedup 1.0000x reference)
//
#include <hip/hip_runtime.h>
#include <stdint.h>
#include <math.h>

typedef float f32x4 __attribute__((ext_vector_type(4)));
typedef __bf16 bf16x8_t __attribute__((ext_vector_type(8)));
typedef unsigned short us8 __attribute__((ext_vector_type(8)));
typedef unsigned short us4 __attribute__((ext_vector_type(4)));
typedef unsigned int u32;

__device__ __forceinline__ unsigned short f2bf(float f) {
  union { float f; uint32_t u; } v; v.f = f;
  uint32_t u = v.u;
  uint32_t r = (u + 0x7fffu + ((u >> 16) & 1u)) >> 16;
  return (unsigned short)r;
}
__device__ __forceinline__ float bf2f(unsigned short h) {
  union { uint32_t u; float f; } v; v.u = ((uint32_t)h) << 16;
  return v.f;
}
__device__ __forceinline__ f32x4 mfma16(us8 a, us8 b, f32x4 c) {
  return __builtin_amdgcn_mfma_f32_16x16x32_bf16(
      __builtin_bit_cast(bf16x8_t, a), __builtin_bit_cast(bf16x8_t, b), c, 0, 0, 0);
}
__device__ __forceinline__ void gl16(const void* g, void* l) {
  __builtin_amdgcn_global_load_lds(
      (const __attribute__((address_space(1))) u32*)g,
      (__attribute__((address_space(3))) u32*)l, 16, 0, 0);
}

// ================= memory plan =================
// d_out: xcat bf16 [32768][2048] @0 (x | mem_read), dead after gemm_f;
//        then out f32 [32768][1024] @0 (gemm_o + ln2 in place);
//        new_values f32 @134217728.
// d_ws:  wft@0 (4MB), wot@4194304 (2MB), keysB@6291456, valT@6553600,
//        w1t@6815744, w2t@7077888, stats1@7110656, stats2@7372800,
//        @7634944: ww bf16 [32768][128] (8MB); partials f32 [64][131072] @+8MB (32MB)
//        fb bf16 [32768][1024] @7634944 (64MB, aliases ww+partials after k_red)

// ---------------- prep ----------------
__global__ __launch_bounds__(256) void k_prep(
    const float* __restrict__ keys, const float* __restrict__ W1,
    const float* __restrict__ W2, const float* __restrict__ Wf,
    const float* __restrict__ Wo, const float* __restrict__ values,
    unsigned short* __restrict__ wft, unsigned short* __restrict__ wot,
    unsigned short* __restrict__ keysB, unsigned short* __restrict__ valT,
    unsigned short* __restrict__ w1t, unsigned short* __restrict__ w2t,
    float* __restrict__ statsz)
{
  int i = blockIdx.x * 256 + threadIdx.x;
  if (i < 2097152) { int k = i >> 10, n = i & 1023; wft[n * 2048 + k] = f2bf(Wf[i]); return; }
  i -= 2097152;
  if (i < 1048576) { int k = i >> 10, n = i & 1023; wot[n * 1024 + k] = f2bf(Wo[i]); return; }
  i -= 1048576;
  if (i < 131072) { keysB[i] = f2bf(keys[i]); return; }
  i -= 131072;
  if (i < 131072) { int s = i >> 10, d = i & 1023; valT[d * 128 + s] = f2bf(values[i]); return; }
  i -= 131072;
  if (i < 131072) { int k = i >> 7, h = i & 127; w1t[h * 1024 + k] = f2bf(W1[i]); return; }
  i -= 131072;
  if (i < 16384) { int h = i >> 7, s = i & 127; w2t[s * 128 + h] = f2bf(W2[i]); return; }
  i -= 16384;
  if (i < 131072) { statsz[i] = 0.f; return; }
}

// ---------------- attention read + write-head (16 rows / block) -------------
// also emits bf16 x into xcat cols [0,1024) (replaces k_castx)
__global__ __launch_bounds__(256) void k_attn(
    const float* __restrict__ x, const unsigned short* __restrict__ keysB,
    const unsigned short* __restrict__ valT, const unsigned short* __restrict__ w1t,
    const unsigned short* __restrict__ w2t, const float* __restrict__ b1,
    const float* __restrict__ b2, const float* __restrict__ temp,
    unsigned short* __restrict__ xcat, unsigned short* __restrict__ ww)
{
  __shared__ unsigned short xq[16][1032];
  __shared__ float lg[16][132];
  __shared__ unsigned short at[16][136];
  __shared__ unsigned short hl[16][136];
  __shared__ float rowinv[16];

  int t = threadIdx.x;
  int row0 = blockIdx.x * 16;

  // x rows f32 -> bf16 -> LDS + xcat
  {
    int r = t >> 4, c4 = (t & 15) * 4;
    const float* xp = x + (size_t)(row0 + r) * 1024;
    unsigned short* xc = xcat + (size_t)(row0 + r) * 2048;
    #pragma unroll
    for (int i = 0; i < 16; ++i) {
      f32x4 v = *(const f32x4*)(xp + i * 64 + c4);
      us4 o;
      #pragma unroll
      for (int e = 0; e < 4; ++e) o[e] = f2bf(v[e]);
      *(us4*)&xq[r][i * 64 + c4] = o;
      *(us4*)(xc + i * 64 + c4) = o;
    }
  }
  __syncthreads();

  int w = t >> 6, l = t & 63, g = l >> 4, lc = l & 15;
  int q2 = w * 2;

  f32x4 acc1[2] = {}; f32x4 acc3[2] = {};
  for (int ks = 0; ks < 32; ++ks) {
    us8 a = *(const us8*)&xq[lc][ks * 32 + g * 8];
    #pragma unroll
    for (int i = 0; i < 2; ++i) {
      int colr = (q2 + i) * 16 + lc;
      us8 bk = *(const us8*)(keysB + (size_t)colr * 1024 + ks * 32 + g * 8);
      acc1[i] = mfma16(a, bk, acc1[i]);
      us8 bw = *(const us8*)(w1t + (size_t)colr * 1024 + ks * 32 + g * 8);
      acc3[i] = mfma16(a, bw, acc3[i]);
    }
  }
  #pragma unroll
  for (int i = 0; i < 2; ++i) {
    int col = (q2 + i) * 16 + lc;
    float bb = b1[col];
    #pragma unroll
    for (int j = 0; j < 4; ++j) {
      int r = g * 4 + j;
      lg[r][col] = acc1[i][j];
      float v = acc3[i][j] + bb;
      v = 0.5f * v * (1.f + erff(v * 0.70710678118654752f));
      hl[r][col] = f2bf(v);
    }
  }
  __syncthreads();

  {
    int r = t >> 4, sub = t & 15;
    float invt = 1.f / fmaxf(temp[0], 1e-6f);
    float vals[8]; float m = -3.4e38f;
    #pragma unroll
    for (int i = 0; i < 8; ++i) { vals[i] = lg[r][sub * 8 + i]; m = fmaxf(m, vals[i]); }
    m = fmaxf(m, __shfl_xor(m, 1)); m = fmaxf(m, __shfl_xor(m, 2));
    m = fmaxf(m, __shfl_xor(m, 4)); m = fmaxf(m, __shfl_xor(m, 8));
    float s = 0.f;
    #pragma unroll
    for (int i = 0; i < 8; ++i) {
      float e = __expf((vals[i] - m) * invt);
      s += e;
      at[r][sub * 8 + i] = f2bf(e);
    }
    s += __shfl_xor(s, 1); s += __shfl_xor(s, 2);
    s += __shfl_xor(s, 4); s += __shfl_xor(s, 8);
    if (sub == 0) rowinv[r] = 1.f / s;
  }
  __syncthreads();

  // mem_read -> xcat cols [1024,2048)
  {
    float ri[4];
    #pragma unroll
    for (int j = 0; j < 4; ++j) ri[j] = rowinv[g * 4 + j];
    f32x4 acc[16] = {};
    #pragma unroll
    for (int ks = 0; ks < 4; ++ks) {
      us8 a = *(const us8*)&at[lc][ks * 32 + g * 8];
      #pragma unroll
      for (int i = 0; i < 16; ++i) {
        int dt = w * 16 + i;
        us8 b = *(const us8*)(valT + (size_t)(dt * 16 + lc) * 128 + ks * 32 + g * 8);
        acc[i] = mfma16(a, b, acc[i]);
      }
    }
    #pragma unroll
    for (int i = 0; i < 16; ++i) {
      int dt = w * 16 + i;
      #pragma unroll
      for (int j = 0; j < 4; ++j) {
        int r = row0 + g * 4 + j;
        xcat[(size_t)r * 2048 + 1024 + dt * 16 + lc] = f2bf(acc[i][j] * ri[j]);
      }
    }
  }

  // ww = sigmoid(h@W2 + b2)
  {
    f32x4 acc[2] = {};
    #pragma unroll
    for (int ks = 0; ks < 4; ++ks) {
      us8 a = *(const us8*)&hl[lc][ks * 32 + g * 8];
      #pragma unroll
      for (int i = 0; i < 2; ++i) {
        us8 b = *(const us8*)(w2t + (size_t)((q2 + i) * 16 + lc) * 128 + ks * 32 + g * 8);
        acc[i] = mfma16(a, b, acc[i]);
      }
    }
    #pragma unroll
    for (int i = 0; i < 2; ++i) {
      int col = (q2 + i) * 16 + lc;
      float bb = b2[col];
      #pragma unroll
      for (int j = 0; j < 4; ++j) {
        int r = row0 + g * 4 + j;
        float v = acc[i][j] + bb;
        v = 1.f / (1.f + __expf(-v));
        ww[(size_t)r * 128 + col] = f2bf(v);
      }
    }
  }
}

// ---------------- ww^T @ x  (64 chunks x 8 d-tiles) ----------------
__global__ __launch_bounds__(256) void k_wv(
    const unsigned short* __restrict__ xcat, const unsigned short* __restrict__ ww,
    float* __restrict__ partials)
{
  __shared__ unsigned short wwT[128][40];
  __shared__ unsigned short xT[128][40];
  int t = threadIdx.x;
  int chunk = blockIdx.x >> 3;
  int dt0 = (blockIdx.x & 7) * 128;
  int w = t >> 6, l = t & 63, g = l >> 4, lc = l & 15;
  f32x4 acc[2][8] = {};
  int nn = t >> 3, e0 = (t & 7) * 16;

  for (int ks = 0; ks < 16; ++ks) {
    int n0 = chunk * 512 + ks * 32;
    __syncthreads();
    {
      us8 v0 = *(const us8*)(ww + (size_t)(n0 + nn) * 128 + e0);
      us8 v1 = *(const us8*)(ww + (size_t)(n0 + nn) * 128 + e0 + 8);
      #pragma unroll
      for (int i = 0; i < 8; ++i) { wwT[e0 + i][nn] = v0[i]; wwT[e0 + 8 + i][nn] = v1[i]; }
      const unsigned short* xp = xcat + (size_t)(n0 + nn) * 2048 + dt0 + e0;
      us8 x0 = *(const us8*)xp;
      us8 x1 = *(const us8*)(xp + 8);
      #pragma unroll
      for (int i = 0; i < 8; ++i) { xT[e0 + i][nn] = x0[i]; xT[e0 + 8 + i][nn] = x1[i]; }
    }
    __syncthreads();
    us8 bfr[8];
    #pragma unroll
    for (int i = 0; i < 8; ++i) bfr[i] = *(const us8*)&xT[i * 16 + lc][g * 8];
    #pragma unroll
    for (int st = 0; st < 2; ++st) {
      us8 a = *(const us8*)&wwT[(w * 2 + st) * 16 + lc][g * 8];
      #pragma unroll
      for (int i = 0; i < 8; ++i) acc[st][i] = mfma16(a, bfr[i], acc[st][i]);
    }
  }
  float* p = partials + (size_t)chunk * 131072;
  #pragma unroll
  for (int st = 0; st < 2; ++st)
    #pragma unroll
    for (int i = 0; i < 8; ++i)
      #pragma unroll
      for (int j = 0; j < 4; ++j) {
        int s = (w * 2 + st) * 16 + g * 4 + j;
        p[s * 1024 + dt0 + i * 16 + lc] = acc[st][i][j];
      }
}

__global__ __launch_bounds__(256) void k_red(
    const float* __restrict__ values, const float* __restrict__ partials,
    float* __restrict__ outv)
{
  int i = blockIdx.x * 256 + threadIdx.x;
  float s = 0.f;
  #pragma unroll
  for (int c = 0; c < 64; ++c) s += partials[(size_t)c * 131072 + i];
  outv[i] = values[i] + 0.1f * s;
}

// ---- 128x128 GEMM: 3-deep glds pipeline, counted vmcnt, 1 barrier/step ----
template<int KTOT, int EPI>
__global__ __launch_bounds__(256) void k_gemm(
    const unsigned short* __restrict__ A, const unsigned short* __restrict__ B,
    const float* __restrict__ bias, unsigned short* __restrict__ outF,
    float* __restrict__ outO, const float* __restrict__ resid,
    float* __restrict__ stats)
{
  constexpr int NT = KTOT / 32;
  __shared__ __align__(16) unsigned short Al[3 * 4096];
  __shared__ __align__(16) unsigned short Bl[3 * 4096];

  int t = threadIdx.x;
  int bid = blockIdx.x;
  int cpx = gridDim.x >> 3;
  int logical = (bid & 7) * cpx + (bid >> 3);   // XCD-contiguous tiles
  int m0 = (logical >> 3) * 128, n0 = (logical & 7) * 128;

  // staging: thread t -> rows r, r+64 ; k-slot (t&3)^sw(row) pre-swizzled
  int r = t >> 2, s = t & 3;
  int sp = s ^ (((r >> 1) ^ (r >> 3)) & 3);     // sw(r)==sw(r+64)
  const unsigned short* ga  = A + (size_t)(m0 + r) * KTOT + sp * 8;
  const unsigned short* ga2 = ga + (size_t)64 * KTOT;
  const unsigned short* gb  = B + (size_t)(n0 + r) * KTOT + sp * 8;
  const unsigned short* gb2 = gb + (size_t)64 * KTOT;

  int w = t >> 6, l = t & 63, g = l >> 4, lc = l & 15;
  int wm = w >> 1, wn = w & 1;
  int axo[4], bxo[4];
  #pragma unroll
  for (int i = 0; i < 4; ++i) {
    int row = wm * 64 + i * 16 + lc;
    axo[i] = row * 32 + ((g ^ (((row >> 1) ^ (row >> 3)) & 3)) << 3);
    row = wn * 64 + i * 16 + lc;
    bxo[i] = row * 32 + ((g ^ (((row >> 1) ^ (row >> 3)) & 3)) << 3);
  }

  f32x4 acc[4][4] = {};

  auto stage = [&](int buf, int kt) {
    int off = kt * 32;
    gl16(ga + off,  Al + buf * 4096 + t * 8);
    gl16(ga2 + off, Al + buf * 4096 + 2048 + t * 8);
    gl16(gb + off,  Bl + buf * 4096 + t * 8);
    gl16(gb2 + off, Bl + buf * 4096 + 2048 + t * 8);
  };
  stage(0, 0);
  stage(1, 1);
  int b0 = 0, b1 = 1, b2 = 2;

  for (int kt = 0; kt < NT; ++kt) {
    // own 4 loads of tile kt are the oldest in the FIFO; keep kt+1 in flight
    if (kt + 1 < NT) asm volatile("s_waitcnt vmcnt(4)" ::: "memory");
    else             asm volatile("s_waitcnt vmcnt(0)" ::: "memory");
    __builtin_amdgcn_s_barrier();           // raw barrier: no implicit drain
    if (kt + 2 < NT) stage(b2, kt + 2);
    const unsigned short* Ab = Al + b0 * 4096;
    const unsigned short* Bb = Bl + b0 * 4096;
    us8 a[4], b[4];
    #pragma unroll
    for (int i = 0; i < 4; ++i) a[i] = *(const us8*)(Ab + axo[i]);
    #pragma unroll
    for (int j = 0; j < 4; ++j) b[j] = *(const us8*)(Bb + bxo[j]);
    #pragma unroll
    for (int i = 0; i < 4; ++i)
      #pragma unroll
      for (int j = 0; j < 4; ++j)
        acc[i][j] = mfma16(a[i], b[j], acc[i][j]);
    int tmp = b0; b0 = b1; b1 = b2; b2 = tmp;
  }

  float bv[4];
  #pragma unroll
  for (int jn = 0; jn < 4; ++jn) bv[jn] = bias[n0 + wn * 64 + jn * 16 + lc];
  #pragma unroll
  for (int i = 0; i < 4; ++i) {
    #pragma unroll
    for (int j = 0; j < 4; ++j) {
      int row = m0 + wm * 64 + i * 16 + g * 4 + j;
      float ssum = 0.f, ssq = 0.f;
      #pragma unroll
      for (int jn = 0; jn < 4; ++jn) {
        int col = n0 + wn * 64 + jn * 16 + lc;
        float v = acc[i][jn][j] + bv[jn];
        if (EPI == 1) v += resid[(size_t)row * 1024 + col];
        if (EPI == 0) outF[(size_t)row * 1024 + col] = f2bf(v);
        else          outO[(size_t)row * 1024 + col] = v;
        ssum += v; ssq += v * v;
      }
      #pragma unroll
      for (int msk = 1; msk < 16; msk <<= 1) {
        ssum += __shfl_xor(ssum, msk); ssq += __shfl_xor(ssq, msk);
      }
      if (lc == 0) { atomicAdd(&stats[row * 2], ssum); atomicAdd(&stats[row * 2 + 1], ssq); }
    }
  }
}

// ---------------- LN1 apply in place on fb ----------------
__global__ __launch_bounds__(256) void k_ln1(
    unsigned short* __restrict__ fb, const float* __restrict__ stats1,
    const float* __restrict__ g, const float* __restrict__ b)
{
  int w = threadIdx.x >> 6, l = threadIdx.x & 63;
  int row = blockIdx.x * 4 + w;
  float sA = stats1[row * 2], sB = stats1[row * 2 + 1];
  float mu = sA * (1.f / 1024.f);
  float rs = rsqrtf(sB * (1.f / 1024.f) - mu * mu + 1e-5f);
  unsigned short* p = fb + (size_t)row * 1024 + l * 16;
  us8 v0 = *(const us8*)p;
  us8 v1 = *(const us8*)(p + 8);
  float gv[16], bv[16];
  #pragma unroll
  for (int q = 0; q < 4; ++q) {
    *(f32x4*)&gv[q * 4] = *(const f32x4*)(g + l * 16 + q * 4);
    *(f32x4*)&bv[q * 4] = *(const f32x4*)(b + l * 16 + q * 4);
  }
  us8 o0, o1;
  #pragma unroll
  for (int e = 0; e < 8; ++e) {
    o0[e] = f2bf((bf2f(v0[e]) - mu) * rs * gv[e] + bv[e]);
    o1[e] = f2bf((bf2f(v1[e]) - mu) * rs * gv[e + 8] + bv[e + 8]);
  }
  *(us8*)p = o0;
  *(us8*)(p + 8) = o1;
}

// ---------------- final LN2 in place ----------------
__global__ __launch_bounds__(256) void k_ln2(
    float* __restrict__ out, const float* __restrict__ stats2,
    const float* __restrict__ ln2g, const float* __restrict__ ln2b)
{
  size_t idx = ((size_t)blockIdx.x * 256 + threadIdx.x) * 8;
  int row = (int)(idx >> 10);
  int col = (int)(idx & 1023);
  float sA = stats2[row * 2], sB = stats2[row * 2 + 1];
  float mu = sA * (1.f / 1024.f);
  float rs = rsqrtf(sB * (1.f / 1024.f) - mu * mu + 1e-5f);
  f32x4 t0 = *(const f32x4*)(out + idx);
  f32x4 t1 = *(const f32x4*)(out + idx + 4);
  f32x4 g0 = *(const f32x4*)(ln2g + col), g1 = *(const f32x4*)(ln2g + col + 4);
  f32x4 b0 = *(const f32x4*)(ln2b + col), b1v = *(const f32x4*)(ln2b + col + 4);
  f32x4 o0, o1;
  #pragma unroll
  for (int e = 0; e < 4; ++e) {
    o0[e] = (t0[e] - mu) * rs * g0[e] + b0[e];
    o1[e] = (t1[e] - mu) * rs * g1[e] + b1v[e];
  }
  *(f32x4*)(out + idx) = o0;
  *(f32x4*)(out + idx + 4) = o1;
}

extern "C" void kernel_launch(void* const* d_in, const int* in_sizes, int n_in,
                              void* d_out, int out_size, void* d_ws, size_t ws_size,
                              hipStream_t stream) {
  const float* x      = (const float*)d_in[0];
  const float* keys   = (const float*)d_in[1];
  const float* values = (const float*)d_in[2];
  const float* temp   = (const float*)d_in[3];
  const float* W1     = (const float*)d_in[4];
  const float* b1     = (const float*)d_in[5];
  const float* W2     = (const float*)d_in[6];
  const float* b2     = (const float*)d_in[7];
  const float* Wf     = (const float*)d_in[8];
  const float* bfp    = (const float*)d_in[9];
  const float* ln1g   = (const float*)d_in[10];
  const float* ln1b   = (const float*)d_in[11];
  const float* Wo     = (const float*)d_in[12];
  const float* bo     = (const float*)d_in[13];
  const float* ln2g   = (const float*)d_in[14];
  const float* ln2b   = (const float*)d_in[15];

  char* ws = (char*)d_ws;
  unsigned short* wft   = (unsigned short*)(ws + 0);
  unsigned short* wot   = (unsigned short*)(ws + 4194304);
  unsigned short* keysB = (unsigned short*)(ws + 6291456);
  unsigned short* valT  = (unsigned short*)(ws + 6553600);
  unsigned short* w1t   = (unsigned short*)(ws + 6815744);
  unsigned short* w2t   = (unsigned short*)(ws + 7077888);
  float* stats1         = (float*)(ws + 7110656);
  float* stats2         = (float*)(ws + 7372800);
  unsigned short* ww    = (unsigned short*)(ws + 7634944);
  float* partials       = (float*)(ws + 16023552);
  unsigned short* fb    = (unsigned short*)(ws + 7634944);  // aliases ww+partials (dead)

  unsigned short* xcat  = (unsigned short*)d_out;
  float* out            = (float*)d_out;
  float* newvals        = (float*)((char*)d_out + 134217728);

  k_prep<<<14400, 256, 0, stream>>>(keys, W1, W2, Wf, Wo, values,
                                    wft, wot, keysB, valT, w1t, w2t, stats1);
  k_attn<<<2048, 256, 0, stream>>>(x, keysB, valT, w1t, w2t, b1, b2, temp, xcat, ww);
  k_wv<<<512, 256, 0, stream>>>(xcat, ww, partials);
  k_red<<<512, 256, 0, stream>>>(values, partials, newvals);
  k_gemm<2048, 0><<<2048, 256, 0, stream>>>(xcat, wft, bfp, fb, nullptr, nullptr, stats1);
  k_ln1<<<8192, 256, 0, stream>>>(fb, stats1, ln1g, ln1b);
  k_gemm<1024, 1><<<2048, 256, 0, stream>>>(fb, wot, bo, nullptr, out, x, stats2);
  k_ln2<<<16384, 256, 0, stream>>>(out, stats2, ln2g, ln2b);
}

// Round 4
// 666.929 us; speedup vs baseline: 1.2339x; 1.2339x over previous
//
#include <hip/hip_runtime.h>
#include <stdint.h>
#include <math.h>

typedef float f32x4 __attribute__((ext_vector_type(4)));
typedef __bf16 bf16x8_t __attribute__((ext_vector_type(8)));
typedef unsigned short us8 __attribute__((ext_vector_type(8)));
typedef unsigned short us4 __attribute__((ext_vector_type(4)));
typedef unsigned int u32;

__device__ __forceinline__ unsigned short f2bf(float f) {
  union { float f; uint32_t u; } v; v.f = f;
  uint32_t u = v.u;
  uint32_t r = (u + 0x7fffu + ((u >> 16) & 1u)) >> 16;
  return (unsigned short)r;
}
__device__ __forceinline__ float bf2f(unsigned short h) {
  union { uint32_t u; float f; } v; v.u = ((uint32_t)h) << 16;
  return v.f;
}
__device__ __forceinline__ f32x4 mfma16(us8 a, us8 b, f32x4 c) {
  return __builtin_amdgcn_mfma_f32_16x16x32_bf16(
      __builtin_bit_cast(bf16x8_t, a), __builtin_bit_cast(bf16x8_t, b), c, 0, 0, 0);
}
__device__ __forceinline__ void gl16(const void* g, void* l) {
  __builtin_amdgcn_global_load_lds(
      (const __attribute__((address_space(1))) u32*)g,
      (__attribute__((address_space(3))) u32*)l, 16, 0, 0);
}

// ================= memory plan =================
// d_out: xcat bf16 [32768][2048] @0 (x | mem_read), dead after gemm_f;
//        then out f32 [32768][1024] @0 (gemm_o + ln2 in place);
//        new_values f32 @134217728.
// d_ws:  wft@0 (4MB), wot@4194304 (2MB), keysB@6291456, valT@6553600,
//        w1t@6815744, w2t@7077888, stats1@7110656, stats2@7372800,
//        @7634944: ww bf16 [32768][128] (8MB); partials f32 [64][131072] @+8MB (32MB)
//        fb bf16 [32768][1024] @7634944 (64MB, aliases ww+partials after k_red)

// ---------------- prep ----------------
__global__ __launch_bounds__(256) void k_prep(
    const float* __restrict__ keys, const float* __restrict__ W1,
    const float* __restrict__ W2, const float* __restrict__ Wf,
    const float* __restrict__ Wo, const float* __restrict__ values,
    unsigned short* __restrict__ wft, unsigned short* __restrict__ wot,
    unsigned short* __restrict__ keysB, unsigned short* __restrict__ valT,
    unsigned short* __restrict__ w1t, unsigned short* __restrict__ w2t,
    float* __restrict__ statsz)
{
  int i = blockIdx.x * 256 + threadIdx.x;
  if (i < 2097152) { int k = i >> 10, n = i & 1023; wft[n * 2048 + k] = f2bf(Wf[i]); return; }
  i -= 2097152;
  if (i < 1048576) { int k = i >> 10, n = i & 1023; wot[n * 1024 + k] = f2bf(Wo[i]); return; }
  i -= 1048576;
  if (i < 131072) { keysB[i] = f2bf(keys[i]); return; }
  i -= 131072;
  if (i < 131072) { int s = i >> 10, d = i & 1023; valT[d * 128 + s] = f2bf(values[i]); return; }
  i -= 131072;
  if (i < 131072) { int k = i >> 7, h = i & 127; w1t[h * 1024 + k] = f2bf(W1[i]); return; }
  i -= 131072;
  if (i < 16384) { int h = i >> 7, s = i & 127; w2t[s * 128 + h] = f2bf(W2[i]); return; }
  i -= 16384;
  if (i < 131072) { statsz[i] = 0.f; return; }
}

// ---------------- attention read + write-head (16 rows / block) -------------
__global__ __launch_bounds__(256) void k_attn(
    const float* __restrict__ x, const unsigned short* __restrict__ keysB,
    const unsigned short* __restrict__ valT, const unsigned short* __restrict__ w1t,
    const unsigned short* __restrict__ w2t, const float* __restrict__ b1,
    const float* __restrict__ b2, const float* __restrict__ temp,
    unsigned short* __restrict__ xcat, unsigned short* __restrict__ ww)
{
  __shared__ unsigned short xq[16][1032];
  __shared__ float lg[16][132];
  __shared__ unsigned short at[16][136];
  __shared__ unsigned short hl[16][136];
  __shared__ float rowinv[16];

  int t = threadIdx.x;
  int row0 = blockIdx.x * 16;

  {
    int r = t >> 4, c4 = (t & 15) * 4;
    const float* xp = x + (size_t)(row0 + r) * 1024;
    unsigned short* xc = xcat + (size_t)(row0 + r) * 2048;
    #pragma unroll
    for (int i = 0; i < 16; ++i) {
      f32x4 v = *(const f32x4*)(xp + i * 64 + c4);
      us4 o;
      #pragma unroll
      for (int e = 0; e < 4; ++e) o[e] = f2bf(v[e]);
      *(us4*)&xq[r][i * 64 + c4] = o;
      *(us4*)(xc + i * 64 + c4) = o;
    }
  }
  __syncthreads();

  int w = t >> 6, l = t & 63, g = l >> 4, lc = l & 15;
  int q2 = w * 2;

  f32x4 acc1[2] = {}; f32x4 acc3[2] = {};
  for (int ks = 0; ks < 32; ++ks) {
    us8 a = *(const us8*)&xq[lc][ks * 32 + g * 8];
    #pragma unroll
    for (int i = 0; i < 2; ++i) {
      int colr = (q2 + i) * 16 + lc;
      us8 bk = *(const us8*)(keysB + (size_t)colr * 1024 + ks * 32 + g * 8);
      acc1[i] = mfma16(a, bk, acc1[i]);
      us8 bw = *(const us8*)(w1t + (size_t)colr * 1024 + ks * 32 + g * 8);
      acc3[i] = mfma16(a, bw, acc3[i]);
    }
  }
  #pragma unroll
  for (int i = 0; i < 2; ++i) {
    int col = (q2 + i) * 16 + lc;
    float bb = b1[col];
    #pragma unroll
    for (int j = 0; j < 4; ++j) {
      int r = g * 4 + j;
      lg[r][col] = acc1[i][j];
      float v = acc3[i][j] + bb;
      v = 0.5f * v * (1.f + erff(v * 0.70710678118654752f));
      hl[r][col] = f2bf(v);
    }
  }
  __syncthreads();

  {
    int r = t >> 4, sub = t & 15;
    float invt = 1.f / fmaxf(temp[0], 1e-6f);
    float vals[8]; float m = -3.4e38f;
    #pragma unroll
    for (int i = 0; i < 8; ++i) { vals[i] = lg[r][sub * 8 + i]; m = fmaxf(m, vals[i]); }
    m = fmaxf(m, __shfl_xor(m, 1)); m = fmaxf(m, __shfl_xor(m, 2));
    m = fmaxf(m, __shfl_xor(m, 4)); m = fmaxf(m, __shfl_xor(m, 8));
    float s = 0.f;
    #pragma unroll
    for (int i = 0; i < 8; ++i) {
      float e = __expf((vals[i] - m) * invt);
      s += e;
      at[r][sub * 8 + i] = f2bf(e);
    }
    s += __shfl_xor(s, 1); s += __shfl_xor(s, 2);
    s += __shfl_xor(s, 4); s += __shfl_xor(s, 8);
    if (sub == 0) rowinv[r] = 1.f / s;
  }
  __syncthreads();

  {
    float ri[4];
    #pragma unroll
    for (int j = 0; j < 4; ++j) ri[j] = rowinv[g * 4 + j];
    f32x4 acc[16] = {};
    #pragma unroll
    for (int ks = 0; ks < 4; ++ks) {
      us8 a = *(const us8*)&at[lc][ks * 32 + g * 8];
      #pragma unroll
      for (int i = 0; i < 16; ++i) {
        int dt = w * 16 + i;
        us8 b = *(const us8*)(valT + (size_t)(dt * 16 + lc) * 128 + ks * 32 + g * 8);
        acc[i] = mfma16(a, b, acc[i]);
      }
    }
    #pragma unroll
    for (int i = 0; i < 16; ++i) {
      int dt = w * 16 + i;
      #pragma unroll
      for (int j = 0; j < 4; ++j) {
        int r = row0 + g * 4 + j;
        xcat[(size_t)r * 2048 + 1024 + dt * 16 + lc] = f2bf(acc[i][j] * ri[j]);
      }
    }
  }

  {
    f32x4 acc[2] = {};
    #pragma unroll
    for (int ks = 0; ks < 4; ++ks) {
      us8 a = *(const us8*)&hl[lc][ks * 32 + g * 8];
      #pragma unroll
      for (int i = 0; i < 2; ++i) {
        us8 b = *(const us8*)(w2t + (size_t)((q2 + i) * 16 + lc) * 128 + ks * 32 + g * 8);
        acc[i] = mfma16(a, b, acc[i]);
      }
    }
    #pragma unroll
    for (int i = 0; i < 2; ++i) {
      int col = (q2 + i) * 16 + lc;
      float bb = b2[col];
      #pragma unroll
      for (int j = 0; j < 4; ++j) {
        int r = row0 + g * 4 + j;
        float v = acc[i][j] + bb;
        v = 1.f / (1.f + __expf(-v));
        ww[(size_t)r * 128 + col] = f2bf(v);
      }
    }
  }
}

// ---------------- ww^T @ x  (64 chunks x 8 d-tiles) ----------------
__global__ __launch_bounds__(256) void k_wv(
    const unsigned short* __restrict__ xcat, const unsigned short* __restrict__ ww,
    float* __restrict__ partials)
{
  __shared__ unsigned short wwT[128][40];
  __shared__ unsigned short xT[128][40];
  int t = threadIdx.x;
  int chunk = blockIdx.x >> 3;
  int dt0 = (blockIdx.x & 7) * 128;
  int w = t >> 6, l = t & 63, g = l >> 4, lc = l & 15;
  f32x4 acc[2][8] = {};
  int nn = t >> 3, e0 = (t & 7) * 16;

  for (int ks = 0; ks < 16; ++ks) {
    int n0 = chunk * 512 + ks * 32;
    __syncthreads();
    {
      us8 v0 = *(const us8*)(ww + (size_t)(n0 + nn) * 128 + e0);
      us8 v1 = *(const us8*)(ww + (size_t)(n0 + nn) * 128 + e0 + 8);
      #pragma unroll
      for (int i = 0; i < 8; ++i) { wwT[e0 + i][nn] = v0[i]; wwT[e0 + 8 + i][nn] = v1[i]; }
      const unsigned short* xp = xcat + (size_t)(n0 + nn) * 2048 + dt0 + e0;
      us8 x0 = *(const us8*)xp;
      us8 x1 = *(const us8*)(xp + 8);
      #pragma unroll
      for (int i = 0; i < 8; ++i) { xT[e0 + i][nn] = x0[i]; xT[e0 + 8 + i][nn] = x1[i]; }
    }
    __syncthreads();
    us8 bfr[8];
    #pragma unroll
    for (int i = 0; i < 8; ++i) bfr[i] = *(const us8*)&xT[i * 16 + lc][g * 8];
    #pragma unroll
    for (int st = 0; st < 2; ++st) {
      us8 a = *(const us8*)&wwT[(w * 2 + st) * 16 + lc][g * 8];
      #pragma unroll
      for (int i = 0; i < 8; ++i) acc[st][i] = mfma16(a, bfr[i], acc[st][i]);
    }
  }
  float* p = partials + (size_t)chunk * 131072;
  #pragma unroll
  for (int st = 0; st < 2; ++st)
    #pragma unroll
    for (int i = 0; i < 8; ++i)
      #pragma unroll
      for (int j = 0; j < 4; ++j) {
        int s = (w * 2 + st) * 16 + g * 4 + j;
        p[s * 1024 + dt0 + i * 16 + lc] = acc[st][i][j];
      }
}

__global__ __launch_bounds__(256) void k_red(
    const float* __restrict__ values, const float* __restrict__ partials,
    float* __restrict__ outv)
{
  int i = blockIdx.x * 256 + threadIdx.x;
  float s = 0.f;
  #pragma unroll
  for (int c = 0; c < 64; ++c) s += partials[(size_t)c * 131072 + i];
  outv[i] = values[i] + 0.1f * s;
}

// ---- 256x256 GEMM, BK=64, 512 thr, 8 waves, dbuf glds, counted vmcnt ----
// LDS halfword layout: A buf p @ p*32768, B buf p @ 16384 + p*32768 (128KB)
// A/B tiles stored [256 rows][64 k] with 16B-slot swizzle slot^=(row&7)
// achieved by pre-swizzled GLOBAL source (linear glds dest) + swizzled read.
template<int KTOT, int EPI>
__global__ __launch_bounds__(512, 2) void k_gemm(
    const unsigned short* __restrict__ A, const unsigned short* __restrict__ B,
    const float* __restrict__ bias, unsigned short* __restrict__ outF,
    float* __restrict__ outO, const float* __restrict__ resid,
    float* __restrict__ stats)
{
  constexpr int NT = KTOT / 64;
  __shared__ __align__(16) unsigned short L[65536];

  int t = threadIdx.x;
  int bid = blockIdx.x;
  int cpx = gridDim.x >> 3;
  int logical = (bid & 7) * cpx + (bid >> 3);   // XCD-contiguous (grid%8==0)
  int m0 = (logical >> 2) * 256, n0 = (logical & 3) * 256;

  // ---- staging map: granule gi = j*512 + t ; row = gi>>3 = j*64 + (t>>3);
  // lds slot = t&7 ; global slot = (t&7) ^ (row&7), row&7 = (t>>3)&7 (const in j)
  int srow = t >> 3;
  int gslot = (t & 7) ^ (srow & 7);
  const unsigned short* ga0 = A + (size_t)(m0 + srow) * KTOT + gslot * 8;
  const unsigned short* gb0 = B + (size_t)(n0 + srow) * KTOT + gslot * 8;

  int w = t >> 6, l = t & 63, g = l >> 4, lc = l & 15;
  int wm = w >> 2, wn = w & 3;                  // 2M x 4N waves

  f32x4 acc[8][4] = {};

  auto stage = [&](int p, int kt) {
    int off = kt * 64;
    #pragma unroll
    for (int j = 0; j < 4; ++j)
      gl16(ga0 + (size_t)j * 64 * KTOT + off, L + p * 32768 + j * 4096 + t * 8);
    #pragma unroll
    for (int j = 0; j < 4; ++j)
      gl16(gb0 + (size_t)j * 64 * KTOT + off, L + 16384 + p * 32768 + j * 4096 + t * 8);
  };

  stage(0, 0);
  if (NT > 1) stage(1, 1);

  for (int kt = 0; kt < NT; ++kt) {
    int p = kt & 1;
    if (kt + 1 < NT) asm volatile("s_waitcnt vmcnt(8)" ::: "memory");
    else             asm volatile("s_waitcnt vmcnt(0)" ::: "memory");
    __builtin_amdgcn_s_barrier();

    const unsigned short* Ab = L + p * 32768;
    const unsigned short* Bb = L + 16384 + p * 32768;
    #pragma unroll
    for (int ks = 0; ks < 2; ++ks) {
      us8 av[8], bv[4];
      #pragma unroll
      for (int i = 0; i < 8; ++i) {
        int row = wm * 128 + i * 16 + lc;
        av[i] = *(const us8*)(Ab + row * 64 + (((ks * 4 + g) ^ (lc & 7)) * 8));
      }
      #pragma unroll
      for (int j = 0; j < 4; ++j) {
        int row = wn * 64 + j * 16 + lc;
        bv[j] = *(const us8*)(Bb + row * 64 + (((ks * 4 + g) ^ (lc & 7)) * 8));
      }
      __builtin_amdgcn_s_setprio(1);
      #pragma unroll
      for (int i = 0; i < 8; ++i)
        #pragma unroll
        for (int j = 0; j < 4; ++j)
          acc[i][j] = mfma16(av[i], bv[j], acc[i][j]);
      __builtin_amdgcn_s_setprio(0);
    }
    __builtin_amdgcn_s_barrier();
    if (kt + 2 < NT) stage(p, kt + 2);
  }

  float bv4[4];
  #pragma unroll
  for (int jn = 0; jn < 4; ++jn) bv4[jn] = bias[n0 + wn * 64 + jn * 16 + lc];
  #pragma unroll
  for (int i = 0; i < 8; ++i) {
    #pragma unroll
    for (int jj = 0; jj < 4; ++jj) {
      int row = m0 + wm * 128 + i * 16 + g * 4 + jj;
      float ssum = 0.f, ssq = 0.f;
      #pragma unroll
      for (int jn = 0; jn < 4; ++jn) {
        int col = n0 + wn * 64 + jn * 16 + lc;
        float v = acc[i][jn][jj] + bv4[jn];
        if (EPI == 1) v += resid[(size_t)row * 1024 + col];
        if (EPI == 0) outF[(size_t)row * 1024 + col] = f2bf(v);
        else          outO[(size_t)row * 1024 + col] = v;
        ssum += v; ssq += v * v;
      }
      #pragma unroll
      for (int msk = 1; msk < 16; msk <<= 1) {
        ssum += __shfl_xor(ssum, msk); ssq += __shfl_xor(ssq, msk);
      }
      if (lc == 0) { atomicAdd(&stats[row * 2], ssum); atomicAdd(&stats[row * 2 + 1], ssq); }
    }
  }
}

// ---------------- LN1 apply in place on fb ----------------
__global__ __launch_bounds__(256) void k_ln1(
    unsigned short* __restrict__ fb, const float* __restrict__ stats1,
    const float* __restrict__ g, const float* __restrict__ b)
{
  int w = threadIdx.x >> 6, l = threadIdx.x & 63;
  int row = blockIdx.x * 4 + w;
  float sA = stats1[row * 2], sB = stats1[row * 2 + 1];
  float mu = sA * (1.f / 1024.f);
  float rs = rsqrtf(sB * (1.f / 1024.f) - mu * mu + 1e-5f);
  unsigned short* p = fb + (size_t)row * 1024 + l * 16;
  us8 v0 = *(const us8*)p;
  us8 v1 = *(const us8*)(p + 8);
  float gv[16], bv[16];
  #pragma unroll
  for (int q = 0; q < 4; ++q) {
    *(f32x4*)&gv[q * 4] = *(const f32x4*)(g + l * 16 + q * 4);
    *(f32x4*)&bv[q * 4] = *(const f32x4*)(b + l * 16 + q * 4);
  }
  us8 o0, o1;
  #pragma unroll
  for (int e = 0; e < 8; ++e) {
    o0[e] = f2bf((bf2f(v0[e]) - mu) * rs * gv[e] + bv[e]);
    o1[e] = f2bf((bf2f(v1[e]) - mu) * rs * gv[e + 8] + bv[e + 8]);
  }
  *(us8*)p = o0;
  *(us8*)(p + 8) = o1;
}

// ---------------- final LN2 in place ----------------
__global__ __launch_bounds__(256) void k_ln2(
    float* __restrict__ out, const float* __restrict__ stats2,
    const float* __restrict__ ln2g, const float* __restrict__ ln2b)
{
  size_t idx = ((size_t)blockIdx.x * 256 + threadIdx.x) * 8;
  int row = (int)(idx >> 10);
  int col = (int)(idx & 1023);
  float sA = stats2[row * 2], sB = stats2[row * 2 + 1];
  float mu = sA * (1.f / 1024.f);
  float rs = rsqrtf(sB * (1.f / 1024.f) - mu * mu + 1e-5f);
  f32x4 t0 = *(const f32x4*)(out + idx);
  f32x4 t1 = *(const f32x4*)(out + idx + 4);
  f32x4 g0 = *(const f32x4*)(ln2g + col), g1 = *(const f32x4*)(ln2g + col + 4);
  f32x4 b0 = *(const f32x4*)(ln2b + col), b1v = *(const f32x4*)(ln2b + col + 4);
  f32x4 o0, o1;
  #pragma unroll
  for (int e = 0; e < 4; ++e) {
    o0[e] = (t0[e] - mu) * rs * g0[e] + b0[e];
    o1[e] = (t1[e] - mu) * rs * g1[e] + b1v[e];
  }
  *(f32x4*)(out + idx) = o0;
  *(f32x4*)(out + idx + 4) = o1;
}

extern "C" void kernel_launch(void* const* d_in, const int* in_sizes, int n_in,
                              void* d_out, int out_size, void* d_ws, size_t ws_size,
                              hipStream_t stream) {
  const float* x      = (const float*)d_in[0];
  const float* keys   = (const float*)d_in[1];
  const float* values = (const float*)d_in[2];
  const float* temp   = (const float*)d_in[3];
  const float* W1     = (const float*)d_in[4];
  const float* b1     = (const float*)d_in[5];
  const float* W2     = (const float*)d_in[6];
  const float* b2     = (const float*)d_in[7];
  const float* Wf     = (const float*)d_in[8];
  const float* bfp    = (const float*)d_in[9];
  const float* ln1g   = (const float*)d_in[10];
  const float* ln1b   = (const float*)d_in[11];
  const float* Wo     = (const float*)d_in[12];
  const float* bo     = (const float*)d_in[13];
  const float* ln2g   = (const float*)d_in[14];
  const float* ln2b   = (const float*)d_in[15];

  char* ws = (char*)d_ws;
  unsigned short* wft   = (unsigned short*)(ws + 0);
  unsigned short* wot   = (unsigned short*)(ws + 4194304);
  unsigned short* keysB = (unsigned short*)(ws + 6291456);
  unsigned short* valT  = (unsigned short*)(ws + 6553600);
  unsigned short* w1t   = (unsigned short*)(ws + 6815744);
  unsigned short* w2t   = (unsigned short*)(ws + 7077888);
  float* stats1         = (float*)(ws + 7110656);
  float* stats2         = (float*)(ws + 7372800);
  unsigned short* ww    = (unsigned short*)(ws + 7634944);
  float* partials       = (float*)(ws + 16023552);
  unsigned short* fb    = (unsigned short*)(ws + 7634944);  // aliases ww+partials (dead)

  unsigned short* xcat  = (unsigned short*)d_out;
  float* out            = (float*)d_out;
  float* newvals        = (float*)((char*)d_out + 134217728);

  k_prep<<<14400, 256, 0, stream>>>(keys, W1, W2, Wf, Wo, values,
                                    wft, wot, keysB, valT, w1t, w2t, stats1);
  k_attn<<<2048, 256, 0, stream>>>(x, keysB, valT, w1t, w2t, b1, b2, temp, xcat, ww);
  k_wv<<<512, 256, 0, stream>>>(xcat, ww, partials);
  k_red<<<512, 256, 0, stream>>>(values, partials, newvals);
  k_gemm<2048, 0><<<512, 512, 0, stream>>>(xcat, wft, bfp, fb, nullptr, nullptr, stats1);
  k_ln1<<<8192, 256, 0, stream>>>(fb, stats1, ln1g, ln1b);
  k_gemm<1024, 1><<<512, 512, 0, stream>>>(fb, wot, bo, nullptr, out, x, stats2);
  k_ln2<<<16384, 256, 0, stream>>>(out, stats2, ln2g, ln2b);
}

// Round 5
// 548.010 us; speedup vs baseline: 1.5016x; 1.2170x over previous
//
#include <hip/hip_runtime.h>
#include <stdint.h>
#include <math.h>

typedef float f32x4 __attribute__((ext_vector_type(4)));
typedef __bf16 bf16x8_t __attribute__((ext_vector_type(8)));
typedef unsigned short us8 __attribute__((ext_vector_type(8)));
typedef unsigned short us4 __attribute__((ext_vector_type(4)));
typedef unsigned int u32;

__device__ __forceinline__ unsigned short f2bf(float f) {
  union { float f; uint32_t u; } v; v.f = f;
  uint32_t u = v.u;
  uint32_t r = (u + 0x7fffu + ((u >> 16) & 1u)) >> 16;
  return (unsigned short)r;
}
__device__ __forceinline__ float bf2f(unsigned short h) {
  union { uint32_t u; float f; } v; v.u = ((uint32_t)h) << 16;
  return v.f;
}
__device__ __forceinline__ f32x4 mfma16(us8 a, us8 b, f32x4 c) {
  return __builtin_amdgcn_mfma_f32_16x16x32_bf16(
      __builtin_bit_cast(bf16x8_t, a), __builtin_bit_cast(bf16x8_t, b), c, 0, 0, 0);
}
__device__ __forceinline__ void gl16(const void* g, void* l) {
  __builtin_amdgcn_global_load_lds(
      (const __attribute__((address_space(1))) u32*)g,
      (__attribute__((address_space(3))) u32*)l, 16, 0, 0);
}

// ================= memory plan =================
// d_out: xcat bf16 [32768][2048] @0 (x | mem_read), dead after gemm_f;
//        then out f32 [32768][1024] @0 (gemm_o + ln2 in place);
//        new_values f32 @134217728.
// d_ws:
//   wft  bf16 [1024][2048] @0          (4MB)
//   wot  bf16 [1024][1024] @4194304    (2MB)
//   klw1 bf16 [256][1024]  @6291456    (512KB: rows 0-127 keys, 128-255 W1^T)
//   valT bf16 [1024][128]  @6815744    (256KB)
//   w2t  bf16 [128][128]   @7077888    (32KB)
//   stats1 f32 [32768][2]  @7110656    (256KB)
//   stats2 f32 [32768][2]  @7372800    (256KB)   (stats1+stats2 contiguous)
//   ww   bf16 [32768][128] @7634944    (8MB)
//   lg   f32  [32768][256] @16023552   (32MB)  -> dead after k_smx
//   partials f32 [64][131072] @16023552 (32MB, reuses lg)
//   attn bf16 [32768][128] @49577984   (8MB)   -> dead after k_pv
//   fb   bf16 [32768][1024] @7634944   (64MB, after ww/lg/partials/attn dead)

// ---------------- tiled transpose+cast: dst[c][r] = bf16(src[r][c]) ----------
__global__ __launch_bounds__(256) void k_tr(
    const float* __restrict__ src, unsigned short* __restrict__ dst,
    int R, int C)
{
  __shared__ unsigned short X[64][68];
  int tile = blockIdx.x;
  int tpr = C >> 6;
  int tr = tile / tpr, tc = tile % tpr;
  int t = threadIdx.x;
  int r = t >> 2, c0 = (t & 3) * 16;
  const float* sp = src + (size_t)(tr * 64 + r) * C + tc * 64 + c0;
  #pragma unroll
  for (int q = 0; q < 4; ++q) {
    f32x4 v = *(const f32x4*)(sp + q * 4);
    us4 o;
    #pragma unroll
    for (int e = 0; e < 4; ++e) o[e] = f2bf(v[e]);
    *(us4*)&X[r][c0 + q * 4] = o;
  }
  __syncthreads();
  int o = t >> 2, k0 = (t & 3) * 16;
  us8 w0, w1;
  #pragma unroll
  for (int e = 0; e < 8; ++e) { w0[e] = X[k0 + e][o]; w1[e] = X[k0 + 8 + e][o]; }
  unsigned short* dp = dst + (size_t)(tc * 64 + o) * R + tr * 64 + k0;
  *(us8*)dp = w0;
  *(us8*)(dp + 8) = w1;
}

// ---------------- small prep: keys cast + zero stats ----------------
__global__ __launch_bounds__(256) void k_prep_small(
    const float* __restrict__ keys, unsigned short* __restrict__ klw1,
    float* __restrict__ statsz)
{
  int i = blockIdx.x * 256 + threadIdx.x;
  if (i < 131072) { klw1[i] = f2bf(keys[i]); return; }
  i -= 131072;
  statsz[i] = 0.f;
}

// ---------------- cast x f32 -> xcat cols [0,1024) ----------------
__global__ __launch_bounds__(256) void k_castx(
    const float* __restrict__ x, unsigned short* __restrict__ xcat)
{
  size_t idx = ((size_t)blockIdx.x * 256 + threadIdx.x) * 8;
  int row = (int)(idx >> 10), col = (int)(idx & 1023);
  f32x4 v0 = *(const f32x4*)(x + idx);
  f32x4 v1 = *(const f32x4*)(x + idx + 4);
  us8 o;
  #pragma unroll
  for (int e = 0; e < 4; ++e) { o[e] = f2bf(v0[e]); o[e + 4] = f2bf(v1[e]); }
  *(us8*)(xcat + (size_t)row * 2048 + col) = o;
}

// ---- generic tile GEMM: MTx256 tile, BK=64, 512 thr, dbuf glds, counted vmcnt
// EPI 0: bf16 store + bias + stats     (gemm_f)
// EPI 1: f32 store + bias + resid + stats (gemm_o)
// EPI 2: plain f32 store               (logits)
// EPI 3: plain bf16 store              (pv)
template<int KTOT, int MT, int NTILES, int EPI>
__global__ __launch_bounds__(512, 2) void k_gemm(
    const unsigned short* __restrict__ A, int astride,
    const unsigned short* __restrict__ B,
    const float* __restrict__ bias,
    unsigned short* __restrict__ outB, float* __restrict__ outF,
    int ostride, int ocol,
    const float* __restrict__ resid, float* __restrict__ stats)
{
  constexpr int NT = KTOT / 64;
  constexpr int AHW = MT * 64;
  constexpr int BUFHW = AHW + 16384;
  constexpr int AJ = MT / 64;
  constexpr int IFR = MT / 32;
  __shared__ __align__(16) unsigned short L[2 * BUFHW];

  int t = threadIdx.x;
  int bid = blockIdx.x;
  int cpx = gridDim.x >> 3;
  int logical = (bid & 7) * cpx + (bid >> 3);   // XCD swizzle (grid%8==0)
  int m0 = (logical / NTILES) * MT, n0 = (logical % NTILES) * 256;

  int srow = t >> 3;
  int gslot = (t & 7) ^ (srow & 7);

  int w = t >> 6, l = t & 63, g = l >> 4, lc = l & 15;
  int wm = w >> 2, wn = w & 3;

  f32x4 acc[IFR][4] = {};

  auto stage = [&](int p, int kt) {
    int off = kt * 64 + gslot * 8;
    #pragma unroll
    for (int j = 0; j < AJ; ++j)
      gl16(A + (size_t)(m0 + j * 64 + srow) * astride + off,
           L + p * BUFHW + (j * 64 + srow) * 64 + (t & 7) * 8);
    #pragma unroll
    for (int j = 0; j < 4; ++j)
      gl16(B + (size_t)(n0 + j * 64 + srow) * KTOT + off,
           L + p * BUFHW + AHW + (j * 64 + srow) * 64 + (t & 7) * 8);
  };

  stage(0, 0);
  if (NT > 1) stage(1, 1);

  for (int kt = 0; kt < NT; ++kt) {
    int p = kt & 1;
    if (kt + 1 < NT) {
      if constexpr (AJ + 4 == 6) asm volatile("s_waitcnt vmcnt(6)" ::: "memory");
      else                       asm volatile("s_waitcnt vmcnt(8)" ::: "memory");
    } else {
      asm volatile("s_waitcnt vmcnt(0)" ::: "memory");
    }
    __builtin_amdgcn_s_barrier();

    const unsigned short* Ab = L + p * BUFHW;
    const unsigned short* Bb = L + p * BUFHW + AHW;
    #pragma unroll
    for (int ks = 0; ks < 2; ++ks) {
      us8 av[IFR], bv[4];
      #pragma unroll
      for (int i = 0; i < IFR; ++i) {
        int row = wm * (MT / 2) + i * 16 + lc;
        av[i] = *(const us8*)(Ab + row * 64 + (((ks * 4 + g) ^ (lc & 7)) * 8));
      }
      #pragma unroll
      for (int j = 0; j < 4; ++j) {
        int row = wn * 64 + j * 16 + lc;
        bv[j] = *(const us8*)(Bb + row * 64 + (((ks * 4 + g) ^ (lc & 7)) * 8));
      }
      __builtin_amdgcn_s_setprio(1);
      #pragma unroll
      for (int i = 0; i < IFR; ++i)
        #pragma unroll
        for (int j = 0; j < 4; ++j)
          acc[i][j] = mfma16(av[i], bv[j], acc[i][j]);
      __builtin_amdgcn_s_setprio(0);
    }
    __builtin_amdgcn_s_barrier();
    if (kt + 2 < NT) stage(p, kt + 2);
  }

  float bv4[4];
  if constexpr (EPI <= 1) {
    #pragma unroll
    for (int jn = 0; jn < 4; ++jn) bv4[jn] = bias[n0 + wn * 64 + jn * 16 + lc];
  }
  #pragma unroll
  for (int i = 0; i < IFR; ++i) {
    #pragma unroll
    for (int jj = 0; jj < 4; ++jj) {
      int row = m0 + wm * (MT / 2) + i * 16 + g * 4 + jj;
      float ssum = 0.f, ssq = 0.f;
      #pragma unroll
      for (int jn = 0; jn < 4; ++jn) {
        int col = n0 + wn * 64 + jn * 16 + lc;
        float v = acc[i][jn][jj];
        if constexpr (EPI <= 1) v += bv4[jn];
        if constexpr (EPI == 1) v += resid[(size_t)row * 1024 + col];
        size_t oa = (size_t)row * ostride + ocol + col;
        if constexpr (EPI == 0 || EPI == 3) outB[oa] = f2bf(v);
        else                                outF[oa] = v;
        ssum += v; ssq += v * v;
      }
      if constexpr (EPI <= 1) {
        #pragma unroll
        for (int msk = 1; msk < 16; msk <<= 1) {
          ssum += __shfl_xor(ssum, msk); ssq += __shfl_xor(ssq, msk);
        }
        if (lc == 0) { atomicAdd(&stats[row * 2], ssum); atomicAdd(&stats[row * 2 + 1], ssq); }
      }
    }
  }
}

// ---------------- softmax + gelu + h@W2 -> attn, ww (16 rows/block) ---------
__global__ __launch_bounds__(256) void k_smx(
    const float* __restrict__ lg, const float* __restrict__ b1,
    const float* __restrict__ b2, const float* __restrict__ temp,
    const unsigned short* __restrict__ w2t,
    unsigned short* __restrict__ attn, unsigned short* __restrict__ ww)
{
  __shared__ float lgs[16][260];
  __shared__ unsigned short hl[16][136];
  int t = threadIdx.x;
  int row0 = blockIdx.x * 16;

  {
    int r = t >> 4, c0 = (t & 15) * 16;
    const float* p = lg + (size_t)(row0 + r) * 256 + c0;
    #pragma unroll
    for (int q = 0; q < 4; ++q)
      *(f32x4*)&lgs[r][c0 + q * 4] = *(const f32x4*)(p + q * 4);
  }
  __syncthreads();

  {
    int r = t >> 4, sub = t & 15;
    float invt = 1.f / fmaxf(temp[0], 1e-6f);
    float vals[8]; float m = -3.4e38f;
    #pragma unroll
    for (int i = 0; i < 8; ++i) { vals[i] = lgs[r][sub * 8 + i]; m = fmaxf(m, vals[i]); }
    m = fmaxf(m, __shfl_xor(m, 1)); m = fmaxf(m, __shfl_xor(m, 2));
    m = fmaxf(m, __shfl_xor(m, 4)); m = fmaxf(m, __shfl_xor(m, 8));
    float ev[8]; float s = 0.f;
    #pragma unroll
    for (int i = 0; i < 8; ++i) { ev[i] = __expf((vals[i] - m) * invt); s += ev[i]; }
    s += __shfl_xor(s, 1); s += __shfl_xor(s, 2);
    s += __shfl_xor(s, 4); s += __shfl_xor(s, 8);
    float rinv = 1.f / s;
    us8 av;
    #pragma unroll
    for (int i = 0; i < 8; ++i) av[i] = f2bf(ev[i] * rinv);
    *(us8*)(attn + (size_t)(row0 + r) * 128 + sub * 8) = av;
    #pragma unroll
    for (int i = 0; i < 8; ++i) {
      float v = lgs[r][128 + sub * 8 + i] + b1[sub * 8 + i];
      v = 0.5f * v * (1.f + erff(v * 0.70710678118654752f));
      hl[r][sub * 8 + i] = f2bf(v);
    }
  }
  __syncthreads();

  int w = t >> 6, l = t & 63, g = l >> 4, lc = l & 15;
  int q2 = w * 2;
  f32x4 acc[2] = {};
  #pragma unroll
  for (int ks = 0; ks < 4; ++ks) {
    us8 a = *(const us8*)&hl[lc][ks * 32 + g * 8];
    #pragma unroll
    for (int i = 0; i < 2; ++i) {
      us8 b = *(const us8*)(w2t + (size_t)((q2 + i) * 16 + lc) * 128 + ks * 32 + g * 8);
      acc[i] = mfma16(a, b, acc[i]);
    }
  }
  #pragma unroll
  for (int i = 0; i < 2; ++i) {
    int col = (q2 + i) * 16 + lc;
    float bb = b2[col];
    #pragma unroll
    for (int j = 0; j < 4; ++j) {
      int r = row0 + g * 4 + j;
      float v = acc[i][j] + bb;
      v = 1.f / (1.f + __expf(-v));
      ww[(size_t)r * 128 + col] = f2bf(v);
    }
  }
}

// ---------------- ww^T @ x  (64 chunks x 8 d-tiles) ----------------
__global__ __launch_bounds__(256) void k_wv(
    const unsigned short* __restrict__ xcat, const unsigned short* __restrict__ ww,
    float* __restrict__ partials)
{
  __shared__ unsigned short wwT[128][40];
  __shared__ unsigned short xT[128][40];
  int t = threadIdx.x;
  int chunk = blockIdx.x >> 3;
  int dt0 = (blockIdx.x & 7) * 128;
  int w = t >> 6, l = t & 63, g = l >> 4, lc = l & 15;
  f32x4 acc[2][8] = {};
  int nn = t >> 3, e0 = (t & 7) * 16;

  for (int ks = 0; ks < 16; ++ks) {
    int n0 = chunk * 512 + ks * 32;
    __syncthreads();
    {
      us8 v0 = *(const us8*)(ww + (size_t)(n0 + nn) * 128 + e0);
      us8 v1 = *(const us8*)(ww + (size_t)(n0 + nn) * 128 + e0 + 8);
      #pragma unroll
      for (int i = 0; i < 8; ++i) { wwT[e0 + i][nn] = v0[i]; wwT[e0 + 8 + i][nn] = v1[i]; }
      const unsigned short* xp = xcat + (size_t)(n0 + nn) * 2048 + dt0 + e0;
      us8 x0 = *(const us8*)xp;
      us8 x1 = *(const us8*)(xp + 8);
      #pragma unroll
      for (int i = 0; i < 8; ++i) { xT[e0 + i][nn] = x0[i]; xT[e0 + 8 + i][nn] = x1[i]; }
    }
    __syncthreads();
    us8 bfr[8];
    #pragma unroll
    for (int i = 0; i < 8; ++i) bfr[i] = *(const us8*)&xT[i * 16 + lc][g * 8];
    #pragma unroll
    for (int st = 0; st < 2; ++st) {
      us8 a = *(const us8*)&wwT[(w * 2 + st) * 16 + lc][g * 8];
      #pragma unroll
      for (int i = 0; i < 8; ++i) acc[st][i] = mfma16(a, bfr[i], acc[st][i]);
    }
  }
  float* p = partials + (size_t)chunk * 131072;
  #pragma unroll
  for (int st = 0; st < 2; ++st)
    #pragma unroll
    for (int i = 0; i < 8; ++i)
      #pragma unroll
      for (int j = 0; j < 4; ++j) {
        int s = (w * 2 + st) * 16 + g * 4 + j;
        p[s * 1024 + dt0 + i * 16 + lc] = acc[st][i][j];
      }
}

__global__ __launch_bounds__(256) void k_red(
    const float* __restrict__ values, const float* __restrict__ partials,
    float* __restrict__ outv)
{
  int i = blockIdx.x * 256 + threadIdx.x;
  float s = 0.f;
  #pragma unroll
  for (int c = 0; c < 64; ++c) s += partials[(size_t)c * 131072 + i];
  outv[i] = values[i] + 0.1f * s;
}

// ---------------- LN1 apply in place on fb ----------------
__global__ __launch_bounds__(256) void k_ln1(
    unsigned short* __restrict__ fb, const float* __restrict__ stats1,
    const float* __restrict__ g, const float* __restrict__ b)
{
  int w = threadIdx.x >> 6, l = threadIdx.x & 63;
  int row = blockIdx.x * 4 + w;
  float sA = stats1[row * 2], sB = stats1[row * 2 + 1];
  float mu = sA * (1.f / 1024.f);
  float rs = rsqrtf(sB * (1.f / 1024.f) - mu * mu + 1e-5f);
  unsigned short* p = fb + (size_t)row * 1024 + l * 16;
  us8 v0 = *(const us8*)p;
  us8 v1 = *(const us8*)(p + 8);
  float gv[16], bv[16];
  #pragma unroll
  for (int q = 0; q < 4; ++q) {
    *(f32x4*)&gv[q * 4] = *(const f32x4*)(g + l * 16 + q * 4);
    *(f32x4*)&bv[q * 4] = *(const f32x4*)(b + l * 16 + q * 4);
  }
  us8 o0, o1;
  #pragma unroll
  for (int e = 0; e < 8; ++e) {
    o0[e] = f2bf((bf2f(v0[e]) - mu) * rs * gv[e] + bv[e]);
    o1[e] = f2bf((bf2f(v1[e]) - mu) * rs * gv[e + 8] + bv[e + 8]);
  }
  *(us8*)p = o0;
  *(us8*)(p + 8) = o1;
}

// ---------------- final LN2 in place ----------------
__global__ __launch_bounds__(256) void k_ln2(
    float* __restrict__ out, const float* __restrict__ stats2,
    const float* __restrict__ ln2g, const float* __restrict__ ln2b)
{
  size_t idx = ((size_t)blockIdx.x * 256 + threadIdx.x) * 8;
  int row = (int)(idx >> 10);
  int col = (int)(idx & 1023);
  float sA = stats2[row * 2], sB = stats2[row * 2 + 1];
  float mu = sA * (1.f / 1024.f);
  float rs = rsqrtf(sB * (1.f / 1024.f) - mu * mu + 1e-5f);
  f32x4 t0 = *(const f32x4*)(out + idx);
  f32x4 t1 = *(const f32x4*)(out + idx + 4);
  f32x4 g0 = *(const f32x4*)(ln2g + col), g1 = *(const f32x4*)(ln2g + col + 4);
  f32x4 b0 = *(const f32x4*)(ln2b + col), b1v = *(const f32x4*)(ln2b + col + 4);
  f32x4 o0, o1;
  #pragma unroll
  for (int e = 0; e < 4; ++e) {
    o0[e] = (t0[e] - mu) * rs * g0[e] + b0[e];
    o1[e] = (t1[e] - mu) * rs * g1[e] + b1v[e];
  }
  *(f32x4*)(out + idx) = o0;
  *(f32x4*)(out + idx + 4) = o1;
}

extern "C" void kernel_launch(void* const* d_in, const int* in_sizes, int n_in,
                              void* d_out, int out_size, void* d_ws, size_t ws_size,
                              hipStream_t stream) {
  const float* x      = (const float*)d_in[0];
  const float* keys   = (const float*)d_in[1];
  const float* values = (const float*)d_in[2];
  const float* temp   = (const float*)d_in[3];
  const float* W1     = (const float*)d_in[4];
  const float* b1     = (const float*)d_in[5];
  const float* W2     = (const float*)d_in[6];
  const float* b2     = (const float*)d_in[7];
  const float* Wf     = (const float*)d_in[8];
  const float* bfp    = (const float*)d_in[9];
  const float* ln1g   = (const float*)d_in[10];
  const float* ln1b   = (const float*)d_in[11];
  const float* Wo     = (const float*)d_in[12];
  const float* bo     = (const float*)d_in[13];
  const float* ln2g   = (const float*)d_in[14];
  const float* ln2b   = (const float*)d_in[15];

  char* ws = (char*)d_ws;
  unsigned short* wft   = (unsigned short*)(ws + 0);
  unsigned short* wot   = (unsigned short*)(ws + 4194304);
  unsigned short* klw1  = (unsigned short*)(ws + 6291456);
  unsigned short* valT  = (unsigned short*)(ws + 6815744);
  unsigned short* w2t   = (unsigned short*)(ws + 7077888);
  float* stats1         = (float*)(ws + 7110656);
  float* stats2         = (float*)(ws + 7372800);
  unsigned short* ww    = (unsigned short*)(ws + 7634944);
  float* lg             = (float*)(ws + 16023552);
  float* partials       = (float*)(ws + 16023552);   // reuses lg (dead)
  unsigned short* attn  = (unsigned short*)(ws + 49577984);
  unsigned short* fb    = (unsigned short*)(ws + 7634944);  // after ww/lg/attn dead

  unsigned short* xcat  = (unsigned short*)d_out;
  float* out            = (float*)d_out;
  float* newvals        = (float*)((char*)d_out + 134217728);

  k_tr<<<512, 256, 0, stream>>>(Wf, wft, 2048, 1024);
  k_tr<<<256, 256, 0, stream>>>(Wo, wot, 1024, 1024);
  k_tr<<<32, 256, 0, stream>>>(W1, klw1 + 131072, 1024, 128);
  k_tr<<<32, 256, 0, stream>>>(values, valT, 128, 1024);
  k_tr<<<4, 256, 0, stream>>>(W2, w2t, 128, 128);
  k_prep_small<<<1024, 256, 0, stream>>>(keys, klw1, stats1);
  k_castx<<<16384, 256, 0, stream>>>(x, xcat);

  k_gemm<1024, 128, 1, 2><<<256, 512, 0, stream>>>(
      xcat, 2048, klw1, nullptr, nullptr, lg, 256, 0, nullptr, nullptr);
  k_smx<<<2048, 256, 0, stream>>>(lg, b1, b2, temp, w2t, attn, ww);
  k_gemm<128, 256, 4, 3><<<512, 512, 0, stream>>>(
      attn, 128, valT, nullptr, xcat, nullptr, 2048, 1024, nullptr, nullptr);

  k_wv<<<512, 256, 0, stream>>>(xcat, ww, partials);
  k_red<<<512, 256, 0, stream>>>(values, partials, newvals);

  k_gemm<2048, 256, 4, 0><<<512, 512, 0, stream>>>(
      xcat, 2048, wft, bfp, fb, nullptr, 1024, 0, nullptr, stats1);
  k_ln1<<<8192, 256, 0, stream>>>(fb, stats1, ln1g, ln1b);
  k_gemm<1024, 256, 4, 1><<<512, 512, 0, stream>>>(
      fb, 1024, wot, bo, nullptr, out, 1024, 0, x, stats2);
  k_ln2<<<16384, 256, 0, stream>>>(out, stats2, ln2g, ln2b);
}

// Round 6
// 545.840 us; speedup vs baseline: 1.5076x; 1.0040x over previous
//
#include <hip/hip_runtime.h>
#include <stdint.h>
#include <math.h>

typedef float f32x4 __attribute__((ext_vector_type(4)));
typedef __bf16 bf16x8_t __attribute__((ext_vector_type(8)));
typedef unsigned short us8 __attribute__((ext_vector_type(8)));
typedef unsigned short us4 __attribute__((ext_vector_type(4)));
typedef unsigned int u32;

__device__ __forceinline__ unsigned short f2bf(float f) {
  union { float f; uint32_t u; } v; v.f = f;
  uint32_t u = v.u;
  uint32_t r = (u + 0x7fffu + ((u >> 16) & 1u)) >> 16;
  return (unsigned short)r;
}
__device__ __forceinline__ float bf2f(unsigned short h) {
  union { uint32_t u; float f; } v; v.u = ((uint32_t)h) << 16;
  return v.f;
}
__device__ __forceinline__ f32x4 mfma16(us8 a, us8 b, f32x4 c) {
  return __builtin_amdgcn_mfma_f32_16x16x32_bf16(
      __builtin_bit_cast(bf16x8_t, a), __builtin_bit_cast(bf16x8_t, b), c, 0, 0, 0);
}
__device__ __forceinline__ void gl16(const void* g, void* l) {
  __builtin_amdgcn_global_load_lds(
      (const __attribute__((address_space(1))) u32*)g,
      (__attribute__((address_space(3))) u32*)l, 16, 0, 0);
}

// ================= memory plan (unchanged from round 5) =================
// d_out: xcat bf16 [32768][2048] @0 ; then out f32 [32768][1024] @0 ;
//        new_values f32 @134217728.
// d_ws: wft@0, wot@4194304, klw1@6291456, valT@6815744, w2t@7077888,
//       stats1@7110656, stats2@7372800, ww@7634944, lg/partials@16023552,
//       attn@49577984, fb@7634944 (after ww/lg/attn dead)

// ---------------- tiled transpose+cast ----------------
__global__ __launch_bounds__(256) void k_tr(
    const float* __restrict__ src, unsigned short* __restrict__ dst,
    int R, int C)
{
  __shared__ unsigned short X[64][68];
  int tile = blockIdx.x;
  int tpr = C >> 6;
  int tr = tile / tpr, tc = tile % tpr;
  int t = threadIdx.x;
  int r = t >> 2, c0 = (t & 3) * 16;
  const float* sp = src + (size_t)(tr * 64 + r) * C + tc * 64 + c0;
  #pragma unroll
  for (int q = 0; q < 4; ++q) {
    f32x4 v = *(const f32x4*)(sp + q * 4);
    us4 o;
    #pragma unroll
    for (int e = 0; e < 4; ++e) o[e] = f2bf(v[e]);
    *(us4*)&X[r][c0 + q * 4] = o;
  }
  __syncthreads();
  int o = t >> 2, k0 = (t & 3) * 16;
  us8 w0, w1;
  #pragma unroll
  for (int e = 0; e < 8; ++e) { w0[e] = X[k0 + e][o]; w1[e] = X[k0 + 8 + e][o]; }
  unsigned short* dp = dst + (size_t)(tc * 64 + o) * R + tr * 64 + k0;
  *(us8*)dp = w0;
  *(us8*)(dp + 8) = w1;
}

// ---------------- small prep ----------------
__global__ __launch_bounds__(256) void k_prep_small(
    const float* __restrict__ keys, unsigned short* __restrict__ klw1,
    float* __restrict__ statsz)
{
  int i = blockIdx.x * 256 + threadIdx.x;
  if (i < 131072) { klw1[i] = f2bf(keys[i]); return; }
  i -= 131072;
  statsz[i] = 0.f;
}

// ---------------- cast x ----------------
__global__ __launch_bounds__(256) void k_castx(
    const float* __restrict__ x, unsigned short* __restrict__ xcat)
{
  size_t idx = ((size_t)blockIdx.x * 256 + threadIdx.x) * 8;
  int row = (int)(idx >> 10), col = (int)(idx & 1023);
  f32x4 v0 = *(const f32x4*)(x + idx);
  f32x4 v1 = *(const f32x4*)(x + idx + 4);
  us8 o;
  #pragma unroll
  for (int e = 0; e < 4; ++e) { o[e] = f2bf(v0[e]); o[e + 4] = f2bf(v1[e]); }
  *(us8*)(xcat + (size_t)row * 2048 + col) = o;
}

// ======== 8-phase 256x256 GEMM (T2+T3+T4+T5), N fixed at 1024 ========
// LDS (halfwords): A[p][ks][256 rows][32 k] @ p*16384 + ks*8192
//                  B[...] @ 32768 + same. Total 65536 HW = 128 KB.
// granule (16B) within ks-region: idx = row*4 + (g ^ ((row>>1)&3)).
// Stage = one ks-half of A or B (1024 granules, 2 gl16/thread), linear dest,
// pre-swizzled global source. vmcnt(4) at phase ends 1 & 3 only.
template<int KTOT, int EPI>
__global__ __launch_bounds__(512, 2) void k_gemm8(
    const unsigned short* __restrict__ A, int astride,
    const unsigned short* __restrict__ B,
    const float* __restrict__ bias,
    unsigned short* __restrict__ outB, float* __restrict__ outF,
    int ostride, int ocol,
    const float* __restrict__ resid, float* __restrict__ stats)
{
  constexpr int NT = KTOT / 64;
  __shared__ __align__(16) unsigned short L[65536];

  int t = threadIdx.x;
  int bid = blockIdx.x;
  int cpx = gridDim.x >> 3;
  int logical = (bid & 7) * cpx + (bid >> 3);     // XCD swizzle (grid%8==0)
  int m0 = (logical >> 2) * 256, n0 = (logical & 3) * 256;

  // stage source mapping: thread t, sub j -> row j*128 + (t>>2),
  // dest slot t&3 holds source k-slot (t&3)^((t>>3)&3)
  int srow2 = t >> 2;
  int gsrc = (t & 3) ^ ((t >> 3) & 3);

  int w = t >> 6, l = t & 63, g = l >> 4, lc = l & 15;
  int wm = w >> 2, wn = w & 3;                    // 2M x 4N waves
  int swz = (lc >> 1) & 3;

  f32x4 acc[8][4] = {};
  us8 Afr[8], Bfr[2];

  auto stA = [&](int p, int kt, int ks) {
    #pragma unroll
    for (int j = 0; j < 2; ++j)
      gl16(A + (size_t)(m0 + j * 128 + srow2) * astride + kt * 64 + ks * 32 + gsrc * 8,
           L + p * 16384 + ks * 8192 + j * 4096 + t * 8);
  };
  auto stB = [&](int p, int kt, int ks) {
    #pragma unroll
    for (int j = 0; j < 2; ++j)
      gl16(B + (size_t)(n0 + j * 128 + srow2) * KTOT + kt * 64 + ks * 32 + gsrc * 8,
           L + 32768 + p * 16384 + ks * 8192 + j * 4096 + t * 8);
  };
  auto ldA = [&](int p, int ks) {
    const unsigned short* Ab = L + p * 16384 + ks * 8192;
    #pragma unroll
    for (int i = 0; i < 8; ++i) {
      int row = wm * 128 + i * 16 + lc;
      Afr[i] = *(const us8*)(Ab + (size_t)(row * 4 + (g ^ swz)) * 8);
    }
  };
  auto ldB = [&](int p, int ks, int nh) {
    const unsigned short* Bb = L + 32768 + p * 16384 + ks * 8192;
    #pragma unroll
    for (int j2 = 0; j2 < 2; ++j2) {
      int row = wn * 64 + (nh * 2 + j2) * 16 + lc;
      Bfr[j2] = *(const us8*)(Bb + (size_t)(row * 4 + (g ^ swz)) * 8);
    }
  };
  auto quad = [&](int nh) {
    __builtin_amdgcn_s_setprio(1);
    #pragma unroll
    for (int i = 0; i < 8; ++i)
      #pragma unroll
      for (int j2 = 0; j2 < 2; ++j2)
        acc[i][nh * 2 + j2] = mfma16(Afr[i], Bfr[j2], acc[i][nh * 2 + j2]);
    __builtin_amdgcn_s_setprio(0);
  };

  auto tile_phases = [&](int kt, bool donext) {
    int p = kt & 1, q = p ^ 1;
    // ---- phase 0: ks=0, nh=0 ----
    ldA(p, 0);
    ldB(p, 0, 0);
    if (donext) stA(q, kt + 1, 0);
    __builtin_amdgcn_s_barrier();
    quad(0);
    __builtin_amdgcn_s_barrier();
    // ---- phase 1: ks=0, nh=1 ----
    ldB(p, 0, 1);
    if (donext) stB(q, kt + 1, 0);
    __builtin_amdgcn_s_barrier();
    quad(1);
    if (donext) asm volatile("s_waitcnt vmcnt(4)" ::: "memory");
    else        asm volatile("s_waitcnt vmcnt(0)" ::: "memory");
    __builtin_amdgcn_s_barrier();
    // ---- phase 2: ks=1, nh=1 ----
    ldA(p, 1);
    ldB(p, 1, 1);
    if (donext) stA(q, kt + 1, 1);
    __builtin_amdgcn_s_barrier();
    quad(1);
    __builtin_amdgcn_s_barrier();
    // ---- phase 3: ks=1, nh=0 ----
    ldB(p, 1, 0);
    if (donext) stB(q, kt + 1, 1);
    __builtin_amdgcn_s_barrier();
    quad(0);
    if (donext) asm volatile("s_waitcnt vmcnt(4)" ::: "memory");
    __builtin_amdgcn_s_barrier();
  };

  // prologue: stage tile 0 (A0,B0 first -> oldest in FIFO)
  stA(0, 0, 0); stB(0, 0, 0); stA(0, 0, 1); stB(0, 0, 1);
  asm volatile("s_waitcnt vmcnt(4)" ::: "memory");
  __builtin_amdgcn_s_barrier();

  #pragma unroll 1
  for (int kt = 0; kt < NT - 1; ++kt) tile_phases(kt, true);
  tile_phases(NT - 1, false);

  // ---- epilogue ----
  float bv4[4];
  if constexpr (EPI <= 1) {
    #pragma unroll
    for (int jn = 0; jn < 4; ++jn) bv4[jn] = bias[n0 + wn * 64 + jn * 16 + lc];
  }
  #pragma unroll
  for (int i = 0; i < 8; ++i) {
    #pragma unroll
    for (int jj = 0; jj < 4; ++jj) {
      int row = m0 + wm * 128 + i * 16 + g * 4 + jj;
      float ssum = 0.f, ssq = 0.f;
      #pragma unroll
      for (int jn = 0; jn < 4; ++jn) {
        int col = n0 + wn * 64 + jn * 16 + lc;
        float v = acc[i][jn][jj];
        if constexpr (EPI <= 1) v += bv4[jn];
        if constexpr (EPI == 1) v += resid[(size_t)row * 1024 + col];
        size_t oa = (size_t)row * ostride + ocol + col;
        if constexpr (EPI == 0 || EPI == 3) outB[oa] = f2bf(v);
        else                                outF[oa] = v;
        ssum += v; ssq += v * v;
      }
      if constexpr (EPI <= 1) {
        #pragma unroll
        for (int msk = 1; msk < 16; msk <<= 1) {
          ssum += __shfl_xor(ssum, msk); ssq += __shfl_xor(ssq, msk);
        }
        if (lc == 0) { atomicAdd(&stats[row * 2], ssum); atomicAdd(&stats[row * 2 + 1], ssq); }
      }
    }
  }
}

// ---- legacy 2-phase GEMM (kept for the logits GEMM, N=256) ----
template<int KTOT, int MT, int NTILES, int EPI>
__global__ __launch_bounds__(512, 2) void k_gemm(
    const unsigned short* __restrict__ A, int astride,
    const unsigned short* __restrict__ B,
    const float* __restrict__ bias,
    unsigned short* __restrict__ outB, float* __restrict__ outF,
    int ostride, int ocol,
    const float* __restrict__ resid, float* __restrict__ stats)
{
  constexpr int NT = KTOT / 64;
  constexpr int AHW = MT * 64;
  constexpr int BUFHW = AHW + 16384;
  constexpr int AJ = MT / 64;
  constexpr int IFR = MT / 32;
  __shared__ __align__(16) unsigned short L[2 * BUFHW];

  int t = threadIdx.x;
  int bid = blockIdx.x;
  int cpx = gridDim.x >> 3;
  int logical = (bid & 7) * cpx + (bid >> 3);
  int m0 = (logical / NTILES) * MT, n0 = (logical % NTILES) * 256;

  int srow = t >> 3;
  int gslot = (t & 7) ^ (srow & 7);

  int w = t >> 6, l = t & 63, g = l >> 4, lc = l & 15;
  int wm = w >> 2, wn = w & 3;

  f32x4 acc[IFR][4] = {};

  auto stage = [&](int p, int kt) {
    int off = kt * 64 + gslot * 8;
    #pragma unroll
    for (int j = 0; j < AJ; ++j)
      gl16(A + (size_t)(m0 + j * 64 + srow) * astride + off,
           L + p * BUFHW + (j * 64 + srow) * 64 + (t & 7) * 8);
    #pragma unroll
    for (int j = 0; j < 4; ++j)
      gl16(B + (size_t)(n0 + j * 64 + srow) * KTOT + off,
           L + p * BUFHW + AHW + (j * 64 + srow) * 64 + (t & 7) * 8);
  };

  stage(0, 0);
  if (NT > 1) stage(1, 1);

  for (int kt = 0; kt < NT; ++kt) {
    int p = kt & 1;
    if (kt + 1 < NT) {
      if constexpr (AJ + 4 == 6) asm volatile("s_waitcnt vmcnt(6)" ::: "memory");
      else                       asm volatile("s_waitcnt vmcnt(8)" ::: "memory");
    } else {
      asm volatile("s_waitcnt vmcnt(0)" ::: "memory");
    }
    __builtin_amdgcn_s_barrier();

    const unsigned short* Ab = L + p * BUFHW;
    const unsigned short* Bb = L + p * BUFHW + AHW;
    #pragma unroll
    for (int ks = 0; ks < 2; ++ks) {
      us8 av[IFR], bv[4];
      #pragma unroll
      for (int i = 0; i < IFR; ++i) {
        int row = wm * (MT / 2) + i * 16 + lc;
        av[i] = *(const us8*)(Ab + row * 64 + (((ks * 4 + g) ^ (lc & 7)) * 8));
      }
      #pragma unroll
      for (int j = 0; j < 4; ++j) {
        int row = wn * 64 + j * 16 + lc;
        bv[j] = *(const us8*)(Bb + row * 64 + (((ks * 4 + g) ^ (lc & 7)) * 8));
      }
      __builtin_amdgcn_s_setprio(1);
      #pragma unroll
      for (int i = 0; i < IFR; ++i)
        #pragma unroll
        for (int j = 0; j < 4; ++j)
          acc[i][j] = mfma16(av[i], bv[j], acc[i][j]);
      __builtin_amdgcn_s_setprio(0);
    }
    __builtin_amdgcn_s_barrier();
    if (kt + 2 < NT) stage(p, kt + 2);
  }

  #pragma unroll
  for (int i = 0; i < IFR; ++i) {
    #pragma unroll
    for (int jj = 0; jj < 4; ++jj) {
      int row = m0 + wm * (MT / 2) + i * 16 + g * 4 + jj;
      #pragma unroll
      for (int jn = 0; jn < 4; ++jn) {
        int col = n0 + wn * 64 + jn * 16 + lc;
        float v = acc[i][jn][jj];
        size_t oa = (size_t)row * ostride + ocol + col;
        if constexpr (EPI == 0 || EPI == 3) outB[oa] = f2bf(v);
        else                                outF[oa] = v;
      }
    }
  }
}

// ---------------- softmax + gelu + h@W2 -> attn, ww ----------------
__global__ __launch_bounds__(256) void k_smx(
    const float* __restrict__ lg, const float* __restrict__ b1,
    const float* __restrict__ b2, const float* __restrict__ temp,
    const unsigned short* __restrict__ w2t,
    unsigned short* __restrict__ attn, unsigned short* __restrict__ ww)
{
  __shared__ float lgs[16][260];
  __shared__ unsigned short hl[16][136];
  int t = threadIdx.x;
  int row0 = blockIdx.x * 16;

  {
    int r = t >> 4, c0 = (t & 15) * 16;
    const float* p = lg + (size_t)(row0 + r) * 256 + c0;
    #pragma unroll
    for (int q = 0; q < 4; ++q)
      *(f32x4*)&lgs[r][c0 + q * 4] = *(const f32x4*)(p + q * 4);
  }
  __syncthreads();

  {
    int r = t >> 4, sub = t & 15;
    float invt = 1.f / fmaxf(temp[0], 1e-6f);
    float vals[8]; float m = -3.4e38f;
    #pragma unroll
    for (int i = 0; i < 8; ++i) { vals[i] = lgs[r][sub * 8 + i]; m = fmaxf(m, vals[i]); }
    m = fmaxf(m, __shfl_xor(m, 1)); m = fmaxf(m, __shfl_xor(m, 2));
    m = fmaxf(m, __shfl_xor(m, 4)); m = fmaxf(m, __shfl_xor(m, 8));
    float ev[8]; float s = 0.f;
    #pragma unroll
    for (int i = 0; i < 8; ++i) { ev[i] = __expf((vals[i] - m) * invt); s += ev[i]; }
    s += __shfl_xor(s, 1); s += __shfl_xor(s, 2);
    s += __shfl_xor(s, 4); s += __shfl_xor(s, 8);
    float rinv = 1.f / s;
    us8 av;
    #pragma unroll
    for (int i = 0; i < 8; ++i) av[i] = f2bf(ev[i] * rinv);
    *(us8*)(attn + (size_t)(row0 + r) * 128 + sub * 8) = av;
    #pragma unroll
    for (int i = 0; i < 8; ++i) {
      float v = lgs[r][128 + sub * 8 + i] + b1[sub * 8 + i];
      v = 0.5f * v * (1.f + erff(v * 0.70710678118654752f));
      hl[r][sub * 8 + i] = f2bf(v);
    }
  }
  __syncthreads();

  int w = t >> 6, l = t & 63, g = l >> 4, lc = l & 15;
  int q2 = w * 2;
  f32x4 acc[2] = {};
  #pragma unroll
  for (int ks = 0; ks < 4; ++ks) {
    us8 a = *(const us8*)&hl[lc][ks * 32 + g * 8];
    #pragma unroll
    for (int i = 0; i < 2; ++i) {
      us8 b = *(const us8*)(w2t + (size_t)((q2 + i) * 16 + lc) * 128 + ks * 32 + g * 8);
      acc[i] = mfma16(a, b, acc[i]);
    }
  }
  #pragma unroll
  for (int i = 0; i < 2; ++i) {
    int col = (q2 + i) * 16 + lc;
    float bb = b2[col];
    #pragma unroll
    for (int j = 0; j < 4; ++j) {
      int r = row0 + g * 4 + j;
      float v = acc[i][j] + bb;
      v = 1.f / (1.f + __expf(-v));
      ww[(size_t)r * 128 + col] = f2bf(v);
    }
  }
}

// ---------------- ww^T @ x ----------------
__global__ __launch_bounds__(256) void k_wv(
    const unsigned short* __restrict__ xcat, const unsigned short* __restrict__ ww,
    float* __restrict__ partials)
{
  __shared__ unsigned short wwT[128][40];
  __shared__ unsigned short xT[128][40];
  int t = threadIdx.x;
  int chunk = blockIdx.x >> 3;
  int dt0 = (blockIdx.x & 7) * 128;
  int w = t >> 6, l = t & 63, g = l >> 4, lc = l & 15;
  f32x4 acc[2][8] = {};
  int nn = t >> 3, e0 = (t & 7) * 16;

  for (int ks = 0; ks < 16; ++ks) {
    int n0 = chunk * 512 + ks * 32;
    __syncthreads();
    {
      us8 v0 = *(const us8*)(ww + (size_t)(n0 + nn) * 128 + e0);
      us8 v1 = *(const us8*)(ww + (size_t)(n0 + nn) * 128 + e0 + 8);
      #pragma unroll
      for (int i = 0; i < 8; ++i) { wwT[e0 + i][nn] = v0[i]; wwT[e0 + 8 + i][nn] = v1[i]; }
      const unsigned short* xp = xcat + (size_t)(n0 + nn) * 2048 + dt0 + e0;
      us8 x0 = *(const us8*)xp;
      us8 x1 = *(const us8*)(xp + 8);
      #pragma unroll
      for (int i = 0; i < 8; ++i) { xT[e0 + i][nn] = x0[i]; xT[e0 + 8 + i][nn] = x1[i]; }
    }
    __syncthreads();
    us8 bfr[8];
    #pragma unroll
    for (int i = 0; i < 8; ++i) bfr[i] = *(const us8*)&xT[i * 16 + lc][g * 8];
    #pragma unroll
    for (int st = 0; st < 2; ++st) {
      us8 a = *(const us8*)&wwT[(w * 2 + st) * 16 + lc][g * 8];
      #pragma unroll
      for (int i = 0; i < 8; ++i) acc[st][i] = mfma16(a, bfr[i], acc[st][i]);
    }
  }
  float* p = partials + (size_t)chunk * 131072;
  #pragma unroll
  for (int st = 0; st < 2; ++st)
    #pragma unroll
    for (int i = 0; i < 8; ++i)
      #pragma unroll
      for (int j = 0; j < 4; ++j) {
        int s = (w * 2 + st) * 16 + g * 4 + j;
        p[s * 1024 + dt0 + i * 16 + lc] = acc[st][i][j];
      }
}

__global__ __launch_bounds__(256) void k_red(
    const float* __restrict__ values, const float* __restrict__ partials,
    float* __restrict__ outv)
{
  int i = blockIdx.x * 256 + threadIdx.x;
  float s = 0.f;
  #pragma unroll
  for (int c = 0; c < 64; ++c) s += partials[(size_t)c * 131072 + i];
  outv[i] = values[i] + 0.1f * s;
}

// ---------------- LN1 in place on fb ----------------
__global__ __launch_bounds__(256) void k_ln1(
    unsigned short* __restrict__ fb, const float* __restrict__ stats1,
    const float* __restrict__ g, const float* __restrict__ b)
{
  int w = threadIdx.x >> 6, l = threadIdx.x & 63;
  int row = blockIdx.x * 4 + w;
  float sA = stats1[row * 2], sB = stats1[row * 2 + 1];
  float mu = sA * (1.f / 1024.f);
  float rs = rsqrtf(sB * (1.f / 1024.f) - mu * mu + 1e-5f);
  unsigned short* p = fb + (size_t)row * 1024 + l * 16;
  us8 v0 = *(const us8*)p;
  us8 v1 = *(const us8*)(p + 8);
  float gv[16], bv[16];
  #pragma unroll
  for (int q = 0; q < 4; ++q) {
    *(f32x4*)&gv[q * 4] = *(const f32x4*)(g + l * 16 + q * 4);
    *(f32x4*)&bv[q * 4] = *(const f32x4*)(b + l * 16 + q * 4);
  }
  us8 o0, o1;
  #pragma unroll
  for (int e = 0; e < 8; ++e) {
    o0[e] = f2bf((bf2f(v0[e]) - mu) * rs * gv[e] + bv[e]);
    o1[e] = f2bf((bf2f(v1[e]) - mu) * rs * gv[e + 8] + bv[e + 8]);
  }
  *(us8*)p = o0;
  *(us8*)(p + 8) = o1;
}

// ---------------- final LN2 in place ----------------
__global__ __launch_bounds__(256) void k_ln2(
    float* __restrict__ out, const float* __restrict__ stats2,
    const float* __restrict__ ln2g, const float* __restrict__ ln2b)
{
  size_t idx = ((size_t)blockIdx.x * 256 + threadIdx.x) * 8;
  int row = (int)(idx >> 10);
  int col = (int)(idx & 1023);
  float sA = stats2[row * 2], sB = stats2[row * 2 + 1];
  float mu = sA * (1.f / 1024.f);
  float rs = rsqrtf(sB * (1.f / 1024.f) - mu * mu + 1e-5f);
  f32x4 t0 = *(const f32x4*)(out + idx);
  f32x4 t1 = *(const f32x4*)(out + idx + 4);
  f32x4 g0 = *(const f32x4*)(ln2g + col), g1 = *(const f32x4*)(ln2g + col + 4);
  f32x4 b0 = *(const f32x4*)(ln2b + col), b1v = *(const f32x4*)(ln2b + col + 4);
  f32x4 o0, o1;
  #pragma unroll
  for (int e = 0; e < 4; ++e) {
    o0[e] = (t0[e] - mu) * rs * g0[e] + b0[e];
    o1[e] = (t1[e] - mu) * rs * g1[e] + b1v[e];
  }
  *(f32x4*)(out + idx) = o0;
  *(f32x4*)(out + idx + 4) = o1;
}

extern "C" void kernel_launch(void* const* d_in, const int* in_sizes, int n_in,
                              void* d_out, int out_size, void* d_ws, size_t ws_size,
                              hipStream_t stream) {
  const float* x      = (const float*)d_in[0];
  const float* keys   = (const float*)d_in[1];
  const float* values = (const float*)d_in[2];
  const float* temp   = (const float*)d_in[3];
  const float* W1     = (const float*)d_in[4];
  const float* b1     = (const float*)d_in[5];
  const float* W2     = (const float*)d_in[6];
  const float* b2     = (const float*)d_in[7];
  const float* Wf     = (const float*)d_in[8];
  const float* bfp    = (const float*)d_in[9];
  const float* ln1g   = (const float*)d_in[10];
  const float* ln1b   = (const float*)d_in[11];
  const float* Wo     = (const float*)d_in[12];
  const float* bo     = (const float*)d_in[13];
  const float* ln2g   = (const float*)d_in[14];
  const float* ln2b   = (const float*)d_in[15];

  char* ws = (char*)d_ws;
  unsigned short* wft   = (unsigned short*)(ws + 0);
  unsigned short* wot   = (unsigned short*)(ws + 4194304);
  unsigned short* klw1  = (unsigned short*)(ws + 6291456);
  unsigned short* valT  = (unsigned short*)(ws + 6815744);
  unsigned short* w2t   = (unsigned short*)(ws + 7077888);
  float* stats1         = (float*)(ws + 7110656);
  float* stats2         = (float*)(ws + 7372800);
  unsigned short* ww    = (unsigned short*)(ws + 7634944);
  float* lg             = (float*)(ws + 16023552);
  float* partials       = (float*)(ws + 16023552);
  unsigned short* attn  = (unsigned short*)(ws + 49577984);
  unsigned short* fb    = (unsigned short*)(ws + 7634944);

  unsigned short* xcat  = (unsigned short*)d_out;
  float* out            = (float*)d_out;
  float* newvals        = (float*)((char*)d_out + 134217728);

  k_tr<<<512, 256, 0, stream>>>(Wf, wft, 2048, 1024);
  k_tr<<<256, 256, 0, stream>>>(Wo, wot, 1024, 1024);
  k_tr<<<32, 256, 0, stream>>>(W1, klw1 + 131072, 1024, 128);
  k_tr<<<32, 256, 0, stream>>>(values, valT, 128, 1024);
  k_tr<<<4, 256, 0, stream>>>(W2, w2t, 128, 128);
  k_prep_small<<<1024, 256, 0, stream>>>(keys, klw1, stats1);
  k_castx<<<16384, 256, 0, stream>>>(x, xcat);

  k_gemm<1024, 128, 1, 2><<<256, 512, 0, stream>>>(
      xcat, 2048, klw1, nullptr, nullptr, lg, 256, 0, nullptr, nullptr);
  k_smx<<<2048, 256, 0, stream>>>(lg, b1, b2, temp, w2t, attn, ww);
  k_gemm8<128, 3><<<512, 512, 0, stream>>>(
      attn, 128, valT, nullptr, xcat, nullptr, 2048, 1024, nullptr, nullptr);

  k_wv<<<512, 256, 0, stream>>>(xcat, ww, partials);
  k_red<<<512, 256, 0, stream>>>(values, partials, newvals);

  k_gemm8<2048, 0><<<512, 512, 0, stream>>>(
      xcat, 2048, wft, bfp, fb, nullptr, 1024, 0, nullptr, stats1);
  k_ln1<<<8192, 256, 0, stream>>>(fb, stats1, ln1g, ln1b);
  k_gemm8<1024, 1><<<512, 512, 0, stream>>>(
      fb, 1024, wot, bo, nullptr, out, 1024, 0, x, stats2);
  k_ln2<<<16384, 256, 0, stream>>>(out, stats2, ln2g, ln2b);
}